// Round 3
// baseline (220.326 us; speedup 1.0000x reference)
//
#include <hip/hip_runtime.h>
#include <cmath>

// Per-class constants: w[c][j] = normalized (table[c][j]+eps); cst[c] = sum_j w*log(w).
struct KLC {
    float w0[7], w1[7], w2[7], w3[7];
    float cst0, cst1, cst2, cst3;
};

__device__ __forceinline__ float row_kl(const float* __restrict__ x, int t, const KLC& kc) {
    int c = ((unsigned)t <= 2u) ? t : 3;

    float m = x[0];
    #pragma unroll
    for (int j = 1; j < 7; ++j) m = fmaxf(m, x[j]);

    float Z = 0.0f;
    #pragma unroll
    for (int j = 0; j < 7; ++j) Z += __expf(x[j] - m);

    // dot(w_c, v) for all 4 classes, branchless select (VALU has huge headroom)
    float d0 = 0.f, d1 = 0.f, d2 = 0.f, d3 = 0.f;
    #pragma unroll
    for (int j = 0; j < 7; ++j) {
        d0 = fmaf(kc.w0[j], x[j], d0);
        d1 = fmaf(kc.w1[j], x[j], d1);
        d2 = fmaf(kc.w2[j], x[j], d2);
        d3 = fmaf(kc.w3[j], x[j], d3);
    }
    float dw = (c == 0) ? d0 : (c == 1) ? d1 : (c == 2) ? d2 : d3;
    float cs = (c == 0) ? kc.cst0 : (c == 1) ? kc.cst1 : (c == 2) ? kc.cst2 : kc.cst3;

    // sum w*(log w - log p), log p = v - m - logZ (eps-in-log dropped: err << threshold)
    return cs - dw + m + __logf(Z);
}

// One chunk = 1024 rows = 7168 floats = 1792 float4 = 28 KB LDS.
// Stage coalesced (lane-contiguous float4), redistribute via LDS so each
// thread owns 4 consecutive rows.
__global__ __launch_bounds__(256) void kl_main(
    const float* __restrict__ logits,   // [B,7]
    const int*   __restrict__ tgt,      // [B]
    int nchunks,
    double* __restrict__ partial,       // [gridDim.x]
    KLC kc)
{
    __shared__ float lds[7168];
    float4* lds4 = (float4*)lds;
    const float4* __restrict__ lg4 = (const float4*)logits;
    const int4*   __restrict__ tg4 = (const int4*)tgt;

    const int t = threadIdx.x;
    float local = 0.0f;

    for (int ch = blockIdx.x; ch < nchunks; ch += gridDim.x) {
        const long long base4 = (long long)ch * 1792;  // chunk start, float4 units

        // Coalesced global loads: instruction k covers 1024 contiguous bytes/wave.
        float4 r[7];
        #pragma unroll
        for (int k = 0; k < 7; ++k) r[k] = lg4[base4 + k * 256 + t];
        // Targets for the 4 rows this thread will compute (coalesced int4).
        int4 tq = tg4[(long long)ch * 256 + t];

        __syncthreads();                 // prior iteration's LDS reads done
        #pragma unroll
        for (int k = 0; k < 7; ++k) lds4[k * 256 + t] = r[k];   // linear copy
        __syncthreads();

        // This thread's 4 rows = floats [28t, 28t+28) = 7 x b128 at stride 112 B.
        float v[28];
        #pragma unroll
        for (int k = 0; k < 7; ++k) {
            float4 c = lds4[t * 7 + k];
            v[4 * k + 0] = c.x; v[4 * k + 1] = c.y;
            v[4 * k + 2] = c.z; v[4 * k + 3] = c.w;
        }
        int tt[4] = { tq.x, tq.y, tq.z, tq.w };
        #pragma unroll
        for (int rr = 0; rr < 4; ++rr)
            local += row_kl(&v[rr * 7], tt[rr], kc);
    }

    // wave (64) reduction
    #pragma unroll
    for (int off = 32; off > 0; off >>= 1)
        local += __shfl_down(local, off, 64);

    __shared__ float smem[4];
    int lane = threadIdx.x & 63;
    int wid  = threadIdx.x >> 6;
    if (lane == 0) smem[wid] = local;
    __syncthreads();
    if (threadIdx.x == 0)
        partial[blockIdx.x] = (double)(smem[0] + smem[1] + smem[2] + smem[3]);
}

// Final reduce + tail rows (B % 1024) with direct loads.
__global__ __launch_bounds__(256) void kl_reduce(
    const float* __restrict__ logits,
    const int*   __restrict__ tgt,
    long long tail_start, int tail,
    const double* __restrict__ partial, int nb,
    float* __restrict__ out, int B, KLC kc)
{
    double s = 0.0;
    for (int i = threadIdx.x; i < nb; i += 256) s += partial[i];

    float tl = 0.0f;
    for (int r = threadIdx.x; r < tail; r += 256) {
        long long row = tail_start + r;
        float x[7];
        #pragma unroll
        for (int j = 0; j < 7; ++j) x[j] = logits[row * 7 + j];
        tl += row_kl(x, tgt[row], kc);
    }
    s += (double)tl;

    #pragma unroll
    for (int off = 32; off > 0; off >>= 1)
        s += __shfl_down(s, off, 64);

    __shared__ double smem[4];
    int lane = threadIdx.x & 63;
    int wid  = threadIdx.x >> 6;
    if (lane == 0) smem[wid] = s;
    __syncthreads();
    if (threadIdx.x == 0)
        out[0] = (float)((smem[0] + smem[1] + smem[2] + smem[3]) / (double)B);
}

extern "C" void kernel_launch(void* const* d_in, const int* in_sizes, int n_in,
                              void* d_out, int out_size, void* d_ws, size_t ws_size,
                              hipStream_t stream) {
    // d_in[0] = fatigue_logits [B,3] -- unused by the reference, never read
    const float* emotion = (const float*)d_in[1];   // [B,7] float32
    const int*   targets = (const int*)d_in[2];     // [B]   int32
    float*  out     = (float*)d_out;                // scalar
    double* partial = (double*)d_ws;

    const int B = in_sizes[2];                      // 4,000,000
    const int nchunks = B / 1024;                   // full 1024-row chunks
    const int tail = B - nchunks * 1024;            // 256 for B=4M
    const long long tail_start = (long long)nchunks * 1024;

    int nb = 1024;                                  // 4 blocks/CU, grid-stride
    if (nb > nchunks && nchunks > 0) nb = nchunks;
    if ((size_t)nb * sizeof(double) > ws_size)
        nb = (int)(ws_size / sizeof(double));

    // Host-side constant table (double precision, matches reference eps handling)
    static const double T[4][7] = {
        {0.05, 0.02, 0.03, 0.4, 0.05, 0.4, 0.05},
        {0.05, 0.05, 0.05, 0.05, 0.3, 0.05, 0.45},
        {0.1, 0.15, 0.2, 0.02, 0.35, 0.03, 0.15},
        {1.0/7.0, 1.0/7.0, 1.0/7.0, 1.0/7.0, 1.0/7.0, 1.0/7.0, 1.0/7.0},
    };
    const double eps = 1e-8;
    KLC kc;
    float* wrows[4] = { kc.w0, kc.w1, kc.w2, kc.w3 };
    float* csts[4]  = { &kc.cst0, &kc.cst1, &kc.cst2, &kc.cst3 };
    for (int c = 0; c < 4; ++c) {
        double s = 0.0;
        for (int j = 0; j < 7; ++j) s += T[c][j] + eps;
        double cst = 0.0;
        for (int j = 0; j < 7; ++j) {
            double w = (T[c][j] + eps) / s;
            wrows[c][j] = (float)w;
            cst += w * std::log(w);
        }
        *csts[c] = (float)cst;
    }

    kl_main<<<nb, 256, 0, stream>>>(emotion, targets, nchunks, partial, kc);
    kl_reduce<<<1, 256, 0, stream>>>(emotion, targets, tail_start, tail,
                                     partial, nb, out, B, kc);
}

// Round 4
// 200.001 us; speedup vs baseline: 1.1016x; 1.1016x over previous
//
#include <hip/hip_runtime.h>
#include <cmath>

// Per-class constants: w[c][j] = normalized (table[c][j]+eps); cst[c] = sum_j w*log(w).
struct KLC {
    float w0[7], w1[7], w2[7], w3[7];
    float cst0, cst1, cst2, cst3;
};

// KL for one row, all-scalar (NO arrays -> nothing can spill to scratch).
__device__ __forceinline__ float row_kl7(
    float x0, float x1, float x2, float x3, float x4, float x5, float x6,
    int t, const KLC& kc)
{
    int c = ((unsigned)t <= 2u) ? t : 3;

    float m = fmaxf(fmaxf(fmaxf(x0, x1), fmaxf(x2, x3)),
                    fmaxf(fmaxf(x4, x5), x6));

    float Z = __expf(x0 - m) + __expf(x1 - m) + __expf(x2 - m) + __expf(x3 - m)
            + __expf(x4 - m) + __expf(x5 - m) + __expf(x6 - m);

    // dot(w_c, x) for all 4 classes (constants live in SGPRs), branchless select.
    float d0 = fmaf(kc.w0[6], x6, fmaf(kc.w0[5], x5, fmaf(kc.w0[4], x4,
               fmaf(kc.w0[3], x3, fmaf(kc.w0[2], x2, fmaf(kc.w0[1], x1, kc.w0[0] * x0))))));
    float d1 = fmaf(kc.w1[6], x6, fmaf(kc.w1[5], x5, fmaf(kc.w1[4], x4,
               fmaf(kc.w1[3], x3, fmaf(kc.w1[2], x2, fmaf(kc.w1[1], x1, kc.w1[0] * x0))))));
    float d2 = fmaf(kc.w2[6], x6, fmaf(kc.w2[5], x5, fmaf(kc.w2[4], x4,
               fmaf(kc.w2[3], x3, fmaf(kc.w2[2], x2, fmaf(kc.w2[1], x1, kc.w2[0] * x0))))));
    float d3 = fmaf(kc.w3[6], x6, fmaf(kc.w3[5], x5, fmaf(kc.w3[4], x4,
               fmaf(kc.w3[3], x3, fmaf(kc.w3[2], x2, fmaf(kc.w3[1], x1, kc.w3[0] * x0))))));

    float dw = (c == 0) ? d0 : (c == 1) ? d1 : (c == 2) ? d2 : d3;
    float cs = (c == 0) ? kc.cst0 : (c == 1) ? kc.cst1 : (c == 2) ? kc.cst2 : kc.cst3;

    // sum w*(log w - log p), log p = x - m - logZ (eps-in-log dropped: err << threshold)
    return cs - dw + m + __logf(Z);
}

// One chunk = 1024 rows = 7168 floats = 1792 float4 = 28 KB LDS.
// Global side: perfectly coalesced float4 (1024 B per wave instruction).
// LDS side: each thread reads its 4 consecutive rows as 7 float4 registers.
__global__ __launch_bounds__(256) void kl_main(
    const float* __restrict__ logits,   // [B,7]
    const int*   __restrict__ tgt,      // [B]
    int nchunks,
    double* __restrict__ partial,       // [gridDim.x]
    KLC kc)
{
    __shared__ float4 lds4[1792];
    const float4* __restrict__ lg4 = (const float4*)logits;
    const int4*   __restrict__ tg4 = (const int4*)tgt;

    const int t = threadIdx.x;
    float local = 0.0f;

    for (int ch = blockIdx.x; ch < nchunks; ch += gridDim.x) {
        const long long base4 = (long long)ch * 1792;

        // Coalesced global loads — named registers only.
        float4 r0 = lg4[base4 + 0 * 256 + t];
        float4 r1 = lg4[base4 + 1 * 256 + t];
        float4 r2 = lg4[base4 + 2 * 256 + t];
        float4 r3 = lg4[base4 + 3 * 256 + t];
        float4 r4 = lg4[base4 + 4 * 256 + t];
        float4 r5 = lg4[base4 + 5 * 256 + t];
        float4 r6 = lg4[base4 + 6 * 256 + t];
        int4   tq = tg4[(long long)ch * 256 + t];

        __syncthreads();                 // prior iteration's LDS reads done
        lds4[0 * 256 + t] = r0;
        lds4[1 * 256 + t] = r1;
        lds4[2 * 256 + t] = r2;
        lds4[3 * 256 + t] = r3;
        lds4[4 * 256 + t] = r4;
        lds4[5 * 256 + t] = r5;
        lds4[6 * 256 + t] = r6;
        __syncthreads();

        // This thread's 4 rows = float4s [7t, 7t+7)
        float4 c0 = lds4[t * 7 + 0];
        float4 c1 = lds4[t * 7 + 1];
        float4 c2 = lds4[t * 7 + 2];
        float4 c3 = lds4[t * 7 + 3];
        float4 c4 = lds4[t * 7 + 4];
        float4 c5 = lds4[t * 7 + 5];
        float4 c6 = lds4[t * 7 + 6];

        local += row_kl7(c0.x, c0.y, c0.z, c0.w, c1.x, c1.y, c1.z, tq.x, kc);
        local += row_kl7(c1.w, c2.x, c2.y, c2.z, c2.w, c3.x, c3.y, tq.y, kc);
        local += row_kl7(c3.z, c3.w, c4.x, c4.y, c4.z, c4.w, c5.x, tq.z, kc);
        local += row_kl7(c5.y, c5.z, c5.w, c6.x, c6.y, c6.z, c6.w, tq.w, kc);
    }

    // wave (64) reduction
    #pragma unroll
    for (int off = 32; off > 0; off >>= 1)
        local += __shfl_down(local, off, 64);

    __shared__ float smem[4];
    int lane = threadIdx.x & 63;
    int wid  = threadIdx.x >> 6;
    if (lane == 0) smem[wid] = local;
    __syncthreads();
    if (threadIdx.x == 0)
        partial[blockIdx.x] = (double)(smem[0] + smem[1] + smem[2] + smem[3]);
}

// Final reduce + tail rows (B % 1024) with direct scalar loads.
__global__ __launch_bounds__(256) void kl_reduce(
    const float* __restrict__ logits,
    const int*   __restrict__ tgt,
    long long tail_start, int tail,
    const double* __restrict__ partial, int nb,
    float* __restrict__ out, int B, KLC kc)
{
    double s = 0.0;
    for (int i = threadIdx.x; i < nb; i += 256) s += partial[i];

    float tl = 0.0f;
    for (int r = threadIdx.x; r < tail; r += 256) {
        const float* x = logits + (tail_start + r) * 7;
        tl += row_kl7(x[0], x[1], x[2], x[3], x[4], x[5], x[6],
                      tgt[tail_start + r], kc);
    }
    s += (double)tl;

    #pragma unroll
    for (int off = 32; off > 0; off >>= 1)
        s += __shfl_down(s, off, 64);

    __shared__ double smem[4];
    int lane = threadIdx.x & 63;
    int wid  = threadIdx.x >> 6;
    if (lane == 0) smem[wid] = s;
    __syncthreads();
    if (threadIdx.x == 0)
        out[0] = (float)((smem[0] + smem[1] + smem[2] + smem[3]) / (double)B);
}

extern "C" void kernel_launch(void* const* d_in, const int* in_sizes, int n_in,
                              void* d_out, int out_size, void* d_ws, size_t ws_size,
                              hipStream_t stream) {
    // d_in[0] = fatigue_logits [B,3] -- unused by the reference, never read
    const float* emotion = (const float*)d_in[1];   // [B,7] float32
    const int*   targets = (const int*)d_in[2];     // [B]   int32
    float*  out     = (float*)d_out;                // scalar
    double* partial = (double*)d_ws;

    const int B = in_sizes[2];                      // 4,000,000
    const int nchunks = B / 1024;                   // full 1024-row chunks
    const int tail = B - nchunks * 1024;            // 256 for B=4M
    const long long tail_start = (long long)nchunks * 1024;

    int nb = 1024;                                  // grid-stride, ~4 blocks/CU
    if (nb > nchunks && nchunks > 0) nb = nchunks;
    if ((size_t)nb * sizeof(double) > ws_size)
        nb = (int)(ws_size / sizeof(double));

    // Host-side constant table (double precision, matches reference eps handling)
    static const double T[4][7] = {
        {0.05, 0.02, 0.03, 0.4, 0.05, 0.4, 0.05},
        {0.05, 0.05, 0.05, 0.05, 0.3, 0.05, 0.45},
        {0.1, 0.15, 0.2, 0.02, 0.35, 0.03, 0.15},
        {1.0/7.0, 1.0/7.0, 1.0/7.0, 1.0/7.0, 1.0/7.0, 1.0/7.0, 1.0/7.0},
    };
    const double eps = 1e-8;
    KLC kc;
    float* wrows[4] = { kc.w0, kc.w1, kc.w2, kc.w3 };
    float* csts[4]  = { &kc.cst0, &kc.cst1, &kc.cst2, &kc.cst3 };
    for (int c = 0; c < 4; ++c) {
        double s = 0.0;
        for (int j = 0; j < 7; ++j) s += T[c][j] + eps;
        double cst = 0.0;
        for (int j = 0; j < 7; ++j) {
            double w = (T[c][j] + eps) / s;
            wrows[c][j] = (float)w;
            cst += w * std::log(w);
        }
        *csts[c] = (float)cst;
    }

    kl_main<<<nb, 256, 0, stream>>>(emotion, targets, nchunks, partial, kc);
    kl_reduce<<<1, 256, 0, stream>>>(emotion, targets, tail_start, tail,
                                     partial, nb, out, B, kc);
}